// Round 3
// baseline (359.281 us; speedup 1.0000x reference)
//
#include <hip/hip_runtime.h>

// PrototypeLoss: loss = mean_i sum_d (features[i,d] - prototypes[labels[i],d])^2
// N=131072, D=512, C=1000. Output: single fp32 scalar.
//
// Row-per-wave, HBM-bound on the 256 MiB features stream.
// R3 changes vs R2:
//  - dropped __builtin_nontemporal_load on features: the harness restores
//    features right before launch, so lines may still be L3-resident
//    (features == 256 MiB == Infinity Cache size); nt forfeits those hits.
//  - labels for the wave's 16 contiguous rows are prefetched as 4 uniform
//    int4 loads (s_load_dwordx4) before the loop, removing the in-loop
//    s_load -> prototype-gather dependent chain.

typedef float fvec4 __attribute__((ext_vector_type(4)));

constexpr int N_ROWS = 131072;
constexpr int D4     = 128;                   // float4 per row (D = 512)
constexpr int BLOCK  = 256;                   // 4 waves/block
constexpr int GRID   = 2048;                  // 8 blocks/CU
constexpr int WAVES  = GRID * (BLOCK / 64);   // 8192 waves
constexpr int ROWS_PER_WAVE = N_ROWS / WAVES; // 16 contiguous rows per wave

__global__ __launch_bounds__(BLOCK) void proto_loss_main(
    const fvec4* __restrict__ features,    // N_ROWS * D4
    const int*   __restrict__ labels,      // N_ROWS
    const fvec4* __restrict__ prototypes,  // C * D4
    float* __restrict__ partials)          // GRID floats in d_ws
{
    const int lane = threadIdx.x & 63;
    const int wid  = threadIdx.x >> 6;
    // wave-uniform wave index -> scalar addressing for labels/prototype bases
    const int wave = __builtin_amdgcn_readfirstlane(blockIdx.x * (BLOCK / 64) + wid);
    const int row0 = wave * ROWS_PER_WAVE;

    // Prefetch all 16 labels for this wave (uniform addresses -> s_load_dwordx4)
    int labs[ROWS_PER_WAVE];
    {
        const int4* lp = (const int4*)(labels + row0);
        #pragma unroll
        for (int j = 0; j < ROWS_PER_WAVE / 4; ++j) {
            const int4 v = lp[j];
            labs[4 * j + 0] = v.x;
            labs[4 * j + 1] = v.y;
            labs[4 * j + 2] = v.z;
            labs[4 * j + 3] = v.w;
        }
    }

    float acc = 0.0f;
    #pragma unroll 4
    for (int i = 0; i < ROWS_PER_WAVE; ++i) {
        const int row = row0 + i;
        const int lab = __builtin_amdgcn_readfirstlane(labs[i]);
        const long long fbase = (long long)row * D4;
        const fvec4 f0 = features[fbase + lane];
        const fvec4 f1 = features[fbase + 64 + lane];
        const fvec4* prow = prototypes + lab * D4;      // SGPR base
        const fvec4 p0 = prow[lane];
        const fvec4 p1 = prow[lane + 64];

        fvec4 d0 = f0 - p0;
        fvec4 d1 = f1 - p1;
        acc += d0.x * d0.x + d0.y * d0.y + d0.z * d0.z + d0.w * d0.w
             + d1.x * d1.x + d1.y * d1.y + d1.z * d1.z + d1.w * d1.w;
    }

    // wave64 reduce
    #pragma unroll
    for (int off = 32; off > 0; off >>= 1)
        acc += __shfl_down(acc, off, 64);

    __shared__ float wave_sums[BLOCK / 64];
    if (lane == 0) wave_sums[wid] = acc;
    __syncthreads();

    if (threadIdx.x == 0) {
        float s = 0.0f;
        #pragma unroll
        for (int w = 0; w < BLOCK / 64; ++w) s += wave_sums[w];
        partials[blockIdx.x] = s;
    }
}

__global__ __launch_bounds__(BLOCK) void proto_loss_reduce(
    const float* __restrict__ partials, float* __restrict__ out)
{
    float s = 0.0f;
    for (int i = threadIdx.x; i < GRID; i += BLOCK)
        s += partials[i];

    #pragma unroll
    for (int off = 32; off > 0; off >>= 1)
        s += __shfl_down(s, off, 64);

    __shared__ float wave_sums[BLOCK / 64];
    const int lane = threadIdx.x & 63;
    const int wid  = threadIdx.x >> 6;
    if (lane == 0) wave_sums[wid] = s;
    __syncthreads();

    if (threadIdx.x == 0) {
        float t = 0.0f;
        #pragma unroll
        for (int w = 0; w < BLOCK / 64; ++w) t += wave_sums[w];
        out[0] = t * (1.0f / (float)N_ROWS);
    }
}

extern "C" void kernel_launch(void* const* d_in, const int* in_sizes, int n_in,
                              void* d_out, int out_size, void* d_ws, size_t ws_size,
                              hipStream_t stream) {
    const fvec4* features   = (const fvec4*)d_in[0];
    const int*   labels     = (const int*)d_in[1];
    const fvec4* prototypes = (const fvec4*)d_in[2];
    float* partials = (float*)d_ws;   // GRID * 4 bytes of scratch
    float* out      = (float*)d_out;

    proto_loss_main<<<GRID, BLOCK, 0, stream>>>(features, labels, prototypes, partials);
    proto_loss_reduce<<<1, BLOCK, 0, stream>>>(partials, out);
}

// Round 4
// 343.612 us; speedup vs baseline: 1.0456x; 1.0456x over previous
//
#include <hip/hip_runtime.h>

// PrototypeLoss: loss = mean_i sum_d (features[i,d] - prototypes[labels[i],d])^2
// N=131072, D=512, C=1000. Output: single fp32 scalar.
//
// Row-per-wave, HBM-bound on the 256 MiB features stream.
// R4 = R2 + label batch-prefetch, with nontemporal RESTORED:
//  - R3 showed dropping nt regressed +20us: the 1 GiB d_ws poison fill runs
//    between the harness input-restore and our launch, flushing L3 — so plain
//    feature loads gain no L3 hits and instead evict the 2 MiB prototype
//    table from L2. nt keeps the streamed features out of the cache path.
//  - labels for the wave's 16 contiguous rows prefetched as uniform int4
//    loads (s_load_dwordx4) before the loop (removes in-loop dependent
//    s_load -> gather chain; neutral-to-positive).

typedef float fvec4 __attribute__((ext_vector_type(4)));

constexpr int N_ROWS = 131072;
constexpr int D4     = 128;                   // float4 per row (D = 512)
constexpr int BLOCK  = 256;                   // 4 waves/block
constexpr int GRID   = 2048;                  // 8 blocks/CU
constexpr int WAVES  = GRID * (BLOCK / 64);   // 8192 waves
constexpr int ROWS_PER_WAVE = N_ROWS / WAVES; // 16 contiguous rows per wave

__global__ __launch_bounds__(BLOCK) void proto_loss_main(
    const fvec4* __restrict__ features,    // N_ROWS * D4
    const int*   __restrict__ labels,      // N_ROWS
    const fvec4* __restrict__ prototypes,  // C * D4
    float* __restrict__ partials)          // GRID floats in d_ws
{
    const int lane = threadIdx.x & 63;
    const int wid  = threadIdx.x >> 6;
    // wave-uniform wave index -> scalar addressing for labels/prototype bases
    const int wave = __builtin_amdgcn_readfirstlane(blockIdx.x * (BLOCK / 64) + wid);
    const int row0 = wave * ROWS_PER_WAVE;

    // Prefetch all 16 labels for this wave (uniform addresses -> s_load_dwordx4)
    int labs[ROWS_PER_WAVE];
    {
        const int4* lp = (const int4*)(labels + row0);
        #pragma unroll
        for (int j = 0; j < ROWS_PER_WAVE / 4; ++j) {
            const int4 v = lp[j];
            labs[4 * j + 0] = v.x;
            labs[4 * j + 1] = v.y;
            labs[4 * j + 2] = v.z;
            labs[4 * j + 3] = v.w;
        }
    }

    float acc = 0.0f;
    #pragma unroll 4
    for (int i = 0; i < ROWS_PER_WAVE; ++i) {
        const int row = row0 + i;
        const int lab = __builtin_amdgcn_readfirstlane(labs[i]);
        const long long fbase = (long long)row * D4;
        const fvec4 f0 = __builtin_nontemporal_load(features + fbase + lane);
        const fvec4 f1 = __builtin_nontemporal_load(features + fbase + 64 + lane);
        const fvec4* prow = prototypes + lab * D4;      // SGPR base, L2-hot
        const fvec4 p0 = prow[lane];
        const fvec4 p1 = prow[lane + 64];

        fvec4 d0 = f0 - p0;
        fvec4 d1 = f1 - p1;
        acc += d0.x * d0.x + d0.y * d0.y + d0.z * d0.z + d0.w * d0.w
             + d1.x * d1.x + d1.y * d1.y + d1.z * d1.z + d1.w * d1.w;
    }

    // wave64 reduce
    #pragma unroll
    for (int off = 32; off > 0; off >>= 1)
        acc += __shfl_down(acc, off, 64);

    __shared__ float wave_sums[BLOCK / 64];
    if (lane == 0) wave_sums[wid] = acc;
    __syncthreads();

    if (threadIdx.x == 0) {
        float s = 0.0f;
        #pragma unroll
        for (int w = 0; w < BLOCK / 64; ++w) s += wave_sums[w];
        partials[blockIdx.x] = s;
    }
}

__global__ __launch_bounds__(BLOCK) void proto_loss_reduce(
    const float* __restrict__ partials, float* __restrict__ out)
{
    float s = 0.0f;
    for (int i = threadIdx.x; i < GRID; i += BLOCK)
        s += partials[i];

    #pragma unroll
    for (int off = 32; off > 0; off >>= 1)
        s += __shfl_down(s, off, 64);

    __shared__ float wave_sums[BLOCK / 64];
    const int lane = threadIdx.x & 63;
    const int wid  = threadIdx.x >> 6;
    if (lane == 0) wave_sums[wid] = s;
    __syncthreads();

    if (threadIdx.x == 0) {
        float t = 0.0f;
        #pragma unroll
        for (int w = 0; w < BLOCK / 64; ++w) t += wave_sums[w];
        out[0] = t * (1.0f / (float)N_ROWS);
    }
}

extern "C" void kernel_launch(void* const* d_in, const int* in_sizes, int n_in,
                              void* d_out, int out_size, void* d_ws, size_t ws_size,
                              hipStream_t stream) {
    const fvec4* features   = (const fvec4*)d_in[0];
    const int*   labels     = (const int*)d_in[1];
    const fvec4* prototypes = (const fvec4*)d_in[2];
    float* partials = (float*)d_ws;   // GRID * 4 bytes of scratch
    float* out      = (float*)d_out;

    proto_loss_main<<<GRID, BLOCK, 0, stream>>>(features, labels, prototypes, partials);
    proto_loss_reduce<<<1, BLOCK, 0, stream>>>(partials, out);
}

// Round 5
// 340.075 us; speedup vs baseline: 1.0565x; 1.0104x over previous
//
#include <hip/hip_runtime.h>

// PrototypeLoss: loss = mean_i sum_d (features[i,d] - prototypes[labels[i],d])^2
// N=131072, D=512, C=1000. Output: single fp32 scalar.
//
// R5 = exact R2 structure (best measured: 339.3 us), single-variable revert
// of R4's label batch-prefetch (R4: 343.6 us):
//  - row-per-wave: wave-uniform row id -> labels[row] is a scalar s_load,
//    prototype row base in SGPRs; lanes cover the full 512-float row as
//    2 coalesced float4 loads each.
//  - features loaded nontemporal: R3 proved plain loads regress +20us
//    (1 GiB d_ws poison fill flushes L3 pre-launch; plain loads only evict
//    the 2 MiB prototype table from L2).
//  - deterministic two-stage reduction through d_ws (no atomics).
// Kernel-side ~50us vs ~41us HBM floor (268 MB @ 6.6 TB/s); bench metric
// carries ~290us of fixed harness restore/poison traffic.

typedef float fvec4 __attribute__((ext_vector_type(4)));

constexpr int N_ROWS = 131072;
constexpr int D4     = 128;                   // float4 per row (D = 512)
constexpr int BLOCK  = 256;                   // 4 waves/block
constexpr int GRID   = 2048;                  // 8 blocks/CU
constexpr int WAVES  = GRID * (BLOCK / 64);   // 8192 waves
constexpr int ROWS_PER_WAVE = N_ROWS / WAVES; // 16 contiguous rows per wave

__global__ __launch_bounds__(BLOCK) void proto_loss_main(
    const fvec4* __restrict__ features,    // N_ROWS * D4
    const int*   __restrict__ labels,      // N_ROWS
    const fvec4* __restrict__ prototypes,  // C * D4
    float* __restrict__ partials)          // GRID floats in d_ws
{
    const int lane = threadIdx.x & 63;
    const int wid  = threadIdx.x >> 6;
    // wave-uniform wave index -> scalar addressing for labels/prototype bases
    const int wave = __builtin_amdgcn_readfirstlane(blockIdx.x * (BLOCK / 64) + wid);
    const int row0 = wave * ROWS_PER_WAVE;

    float acc = 0.0f;
    #pragma unroll 4
    for (int i = 0; i < ROWS_PER_WAVE; ++i) {
        const int row = row0 + i;                       // SGPR
        const int lab = labels[row];                    // scalar load (uniform addr)
        const long long fbase = (long long)row * D4;
        const fvec4 f0 = __builtin_nontemporal_load(features + fbase + lane);
        const fvec4 f1 = __builtin_nontemporal_load(features + fbase + 64 + lane);
        const fvec4* prow = prototypes + lab * D4;      // SGPR base, L2-hot
        const fvec4 p0 = prow[lane];
        const fvec4 p1 = prow[lane + 64];

        fvec4 d0 = f0 - p0;
        fvec4 d1 = f1 - p1;
        acc += d0.x * d0.x + d0.y * d0.y + d0.z * d0.z + d0.w * d0.w
             + d1.x * d1.x + d1.y * d1.y + d1.z * d1.z + d1.w * d1.w;
    }

    // wave64 reduce
    #pragma unroll
    for (int off = 32; off > 0; off >>= 1)
        acc += __shfl_down(acc, off, 64);

    __shared__ float wave_sums[BLOCK / 64];
    if (lane == 0) wave_sums[wid] = acc;
    __syncthreads();

    if (threadIdx.x == 0) {
        float s = 0.0f;
        #pragma unroll
        for (int w = 0; w < BLOCK / 64; ++w) s += wave_sums[w];
        partials[blockIdx.x] = s;
    }
}

__global__ __launch_bounds__(BLOCK) void proto_loss_reduce(
    const float* __restrict__ partials, float* __restrict__ out)
{
    float s = 0.0f;
    for (int i = threadIdx.x; i < GRID; i += BLOCK)
        s += partials[i];

    #pragma unroll
    for (int off = 32; off > 0; off >>= 1)
        s += __shfl_down(s, off, 64);

    __shared__ float wave_sums[BLOCK / 64];
    const int lane = threadIdx.x & 63;
    const int wid  = threadIdx.x >> 6;
    if (lane == 0) wave_sums[wid] = s;
    __syncthreads();

    if (threadIdx.x == 0) {
        float t = 0.0f;
        #pragma unroll
        for (int w = 0; w < BLOCK / 64; ++w) t += wave_sums[w];
        out[0] = t * (1.0f / (float)N_ROWS);
    }
}

extern "C" void kernel_launch(void* const* d_in, const int* in_sizes, int n_in,
                              void* d_out, int out_size, void* d_ws, size_t ws_size,
                              hipStream_t stream) {
    const fvec4* features   = (const fvec4*)d_in[0];
    const int*   labels     = (const int*)d_in[1];
    const fvec4* prototypes = (const fvec4*)d_in[2];
    float* partials = (float*)d_ws;   // GRID * 4 bytes of scratch
    float* out      = (float*)d_out;

    proto_loss_main<<<GRID, BLOCK, 0, stream>>>(features, labels, prototypes, partials);
    proto_loss_reduce<<<1, BLOCK, 0, stream>>>(partials, out);
}